// Round 12
// baseline (581.346 us; speedup 1.0000x reference)
//
#include <hip/hip_runtime.h>

typedef float    v2f __attribute__((ext_vector_type(2)));
typedef float    v4f __attribute__((ext_vector_type(4)));
typedef int      v4i __attribute__((ext_vector_type(4)));
typedef _Float16 h8  __attribute__((ext_vector_type(8)));

#define TT 1024
#define NIN 6
#define NN 64
#define NB 16        // batches per block (one wave, MFMA cols)
#define CH 4         // steps per staged chunk
#define SCALE 0.09486832980505137f   // sqrt(2*alpha*sigma_rec^2)
#define K2 (0.2f * SCALE)            // alpha folded into noise

typedef const __attribute__((address_space(1))) unsigned int gu32;
typedef __attribute__((address_space(3))) unsigned int lu32;

__device__ __forceinline__ int pkf16(float a, float b) {
  return __builtin_bit_cast(int, __builtin_amdgcn_cvt_pkrtz(a, b));
}

__global__ void __launch_bounds__(64) rnn_scan_kernel(
    const float* __restrict__ u, const float* __restrict__ noise,
    const float* __restrict__ Wrec, const float* __restrict__ Win,
    float* __restrict__ out) {
  const int l = threadIdx.x;
  const int c = l & 15;   // batch column (D col, B col)
  const int q = l >> 4;   // quarter: D rows 4q..4q+3 per tile
  const int B0 = blockIdx.x * NB;

  __shared__ float smNz[2][CH * NB * NN];   // 2 x 16 KB, [st][batch][64] blk-swizzled
  __shared__ float smU[2][CH * NB * NIN];   // 2 x 1.5 KB, [st][batch][6]

  // ---- staging pointers (noise comp-block XOR-swizzled by batch)
  const float* nsrc[4];
#pragma unroll
  for (int i = 0; i < 4; ++i) {
    const int bi = 4 * i + (l >> 4);
    const int blk = (l & 15) ^ (bi & 15);
    nsrc[i] = noise + (size_t)(B0 + bi) * (TT * NN) + 4 * blk;
  }
  const float* usrc[6];
#pragma unroll
  for (int i = 0; i < 6; ++i) {
    const int d = 64 * i + l;
    const int st0 = d / (NB * NIN);
    const int rm = d - st0 * (NB * NIN);
    const int b0 = rm / NIN;
    const int j0 = rm - b0 * NIN;
    usrc[i] = u + (size_t)(B0 + b0) * (TT * NIN) + st0 * NIN + j0;
  }

  // NOTE: offset arg is ALWAYS 0 (R10/R11 used nonzero offsets -- the only
  // new mechanism vs the passing R4-R9 kernels; suspect it offsets the LDS
  // dest too). Distinct source pointers instead.
#define STAGE(BUF) do {                                                        \
    _Pragma("unroll")                                                          \
    for (int i_ = 0; i_ < 4; ++i_) {                                           \
      __builtin_amdgcn_global_load_lds((gu32*)(nsrc[i_]),                      \
          (lu32*)(&smNz[BUF][0 * 1024 + i_ * 256]), 16, 0, 0);                 \
      __builtin_amdgcn_global_load_lds((gu32*)(nsrc[i_] + 64),                 \
          (lu32*)(&smNz[BUF][1 * 1024 + i_ * 256]), 16, 0, 0);                 \
      __builtin_amdgcn_global_load_lds((gu32*)(nsrc[i_] + 128),                \
          (lu32*)(&smNz[BUF][2 * 1024 + i_ * 256]), 16, 0, 0);                 \
      __builtin_amdgcn_global_load_lds((gu32*)(nsrc[i_] + 192),                \
          (lu32*)(&smNz[BUF][3 * 1024 + i_ * 256]), 16, 0, 0);                 \
      nsrc[i_] += CH * NN;                                                     \
    }                                                                          \
    _Pragma("unroll")                                                          \
    for (int i_ = 0; i_ < 6; ++i_) {                                           \
      __builtin_amdgcn_global_load_lds((gu32*)(usrc[i_]),                      \
          (lu32*)(&smU[BUF][i_ * 64]), 4, 0, 0);                               \
      usrc[i_] += CH * NIN;                                                    \
    }                                                                          \
  } while (0)

  // ---- stage chunk 0 immediately (hide behind calibration + weight setup)
  STAGE(0);

  // ---- CALIBRATE A-slot -> B-slot pairing, VGPR-resident (no scratch).
  // Probe: one-hot in A at slot (js,qs) => A = all-ones column k*; with B
  // position-encoded (enc = jb+8*qb+1), D[any] = enc of the B slot holding
  // k*. Lanes with q==qs capture their slot js's pairing.
  int jbv[8], qbv[8];
  {
    h8 benc;
#pragma unroll
    for (int jb = 0; jb < 8; ++jb) benc[jb] = (_Float16)(float)(jb + 8 * q + 1);
    const v4f zc = {0.f, 0.f, 0.f, 0.f};
    const v4i zi4 = {0, 0, 0, 0};
#pragma unroll
    for (int p = 0; p < 32; ++p) {
      const int js = p & 7, qs = p >> 3;
      h8 ap = __builtin_bit_cast(h8, zi4);
      ap[js] = (q == qs) ? (_Float16)1.0f : (_Float16)0.0f;
      const v4f dd = __builtin_amdgcn_mfma_f32_16x16x32_f16(ap, benc, zc, 0, 0, 0);
      const int pc = (int)dd[0] - 1;
      if (qs == q) { jbv[js] = pc & 7; qbv[js] = pc >> 3; }  // js const -> VGPR
    }
  }

  // ---- weight fragments through the measured pairing.
  // B slot (jb,qb) frag kk holds SO[8kk+jb] = state comp
  //   16*((8kk+jb)>>2) + 4*qb + (jb&3)   (repack-definitional).
  // A slot (j,q) of lane c = W row (16T + c) at that comp.
  h8 Ar[4][2], Au[4];
#pragma unroll
  for (int j = 0; j < 8; ++j) {
    const int jb = jbv[j], qb = qbv[j];
#pragma unroll
    for (int kk = 0; kk < 2; ++kk) {
      const int idx = 8 * kk + jb;
      const int comp = 16 * (idx >> 2) + 4 * qb + (jb & 3);
#pragma unroll
      for (int T = 0; T < 4; ++T)
        Ar[T][kk][j] = (_Float16)(0.2f * Wrec[(16 * T + c) * NN + comp]);
    }
    const bool uok = (qb == 0) && (jb < 6);
    const int ju = (jb < 6) ? jb : 0;  // safe address
#pragma unroll
    for (int T = 0; T < 4; ++T) {
      const float wv = 0.2f * Win[(16 * T + c) * NIN + ju];
      Au[T][j] = uok ? (_Float16)wv : (_Float16)0.0f;
    }
  }

  // ---- C-init LDS offsets (swizzle-matched): comp block 4T+q of batch c
  int nzOff[4];
#pragma unroll
  for (int T = 0; T < 4; ++T) nzOff[T] = c * 256 + 16 * ((4 * T + q) ^ c);
  const char* smnzB = (const char*)&smNz[0][0];
  const char* smuB  = (const char*)&smU[0][0];

  // ---- zero row t=0; per-lane output base (comps 16T+4q+0..3 at T*64 bytes)
  char* outP = (char*)(out + (size_t)(B0 + c) * (TT * NN) + 4 * q);
  {
    const v4f z = {0.f, 0.f, 0.f, 0.f};
#pragma unroll
    for (int T = 0; T < 4; ++T) *(v4f*)(outP + 64 * T) = z;
  }

  // ---- state (ping-pong float[16]: SO[4T+r] = comp 16T+4q+r) and B frags
  float sA[16], sB[16];
#pragma unroll
  for (int i = 0; i < 16; ++i) { sA[i] = 0.f; sB[i] = 0.f; }
  const v4i zi = {0, 0, 0, 0};
  h8 Bs0 = __builtin_bit_cast(h8, zi), Bs1 = __builtin_bit_cast(h8, zi);

#define STEP(ST, BUF, SI, SO) do {                                             \
    v4f dT[4];                                                                 \
    _Pragma("unroll")                                                          \
    for (int T_ = 0; T_ < 4; ++T_) {                                           \
      const v4f nz_ = *(const v4f*)(smnzB + (BUF) * 16384 + (ST) * 4096 +      \
                                    nzOff[T_]);                                \
      dT[T_] = v4f{K2 * nz_.x, K2 * nz_.y, K2 * nz_.z, K2 * nz_.w};            \
    }                                                                          \
    const v2f u0_ = *(const v2f*)(smuB + (BUF) * 1536 + (ST) * 384 + c * 24);  \
    const v2f u1_ = *(const v2f*)(smuB + (BUF) * 1536 + (ST) * 384 + c * 24 + 8); \
    const v2f u2_ = *(const v2f*)(smuB + (BUF) * 1536 + (ST) * 384 + c * 24 + 16);\
    h8 bu_ = __builtin_bit_cast(h8, zi);                                       \
    if (q == 0) {                                                              \
      bu_[0] = (_Float16)u0_.x; bu_[1] = (_Float16)u0_.y;                      \
      bu_[2] = (_Float16)u1_.x; bu_[3] = (_Float16)u1_.y;                      \
      bu_[4] = (_Float16)u2_.x; bu_[5] = (_Float16)u2_.y;                      \
    }                                                                          \
    _Pragma("unroll")                                                          \
    for (int T_ = 0; T_ < 4; ++T_) {                                           \
      v4f d_ = __builtin_amdgcn_mfma_f32_16x16x32_f16(Au[T_], bu_, dT[T_], 0, 0, 0); \
      d_ = __builtin_amdgcn_mfma_f32_16x16x32_f16(Ar[T_][0], Bs0, d_, 0, 0, 0);\
      d_ = __builtin_amdgcn_mfma_f32_16x16x32_f16(Ar[T_][1], Bs1, d_, 0, 0, 0);\
      _Pragma("unroll")                                                        \
      for (int r_ = 0; r_ < 4; ++r_)                                           \
        SO[4 * T_ + r_] =                                                      \
            fmaf(SI[4 * T_ + r_], 0.8f, fmaxf(d_[r_], 0.f));                   \
      const v4f sv_ = {SO[4 * T_ + 0], SO[4 * T_ + 1],                         \
                       SO[4 * T_ + 2], SO[4 * T_ + 3]};                        \
      *(v4f*)(outP + ((ST) + 1) * 256 + 64 * T_) = sv_;                        \
    }                                                                          \
    {                                                                          \
      const v4i b0_ = {pkf16(SO[0], SO[1]), pkf16(SO[2], SO[3]),               \
                       pkf16(SO[4], SO[5]), pkf16(SO[6], SO[7])};              \
      const v4i b1_ = {pkf16(SO[8], SO[9]), pkf16(SO[10], SO[11]),             \
                       pkf16(SO[12], SO[13]), pkf16(SO[14], SO[15])};          \
      Bs0 = __builtin_bit_cast(h8, b0_);                                       \
      Bs1 = __builtin_bit_cast(h8, b1_);                                       \
    }                                                                          \
  } while (0)

  // ---- prologue: drain setup, stage chunk 1, consume chunk 0
  asm volatile("s_waitcnt vmcnt(0)" ::: "memory");
  __builtin_amdgcn_sched_barrier(0);
  STAGE(1);
  STEP(0, 0, sA, sB);
  STEP(1, 0, sB, sA);
  STEP(2, 0, sA, sB);
  STEP(3, 0, sB, sA);
  outP += 1024;

  // ---- main: chunks 1..254 (unrolled x2 for literal buffer parity).
  // Per chunk: 22 staged loads then 16 stores; vmcnt(16) retires exactly the
  // pending chunk's loads (issue-order retirement), never drains stores.
  for (int k = 0; k < 127; ++k) {
    asm volatile("s_waitcnt vmcnt(16)" ::: "memory");
    __builtin_amdgcn_sched_barrier(0);
    STAGE(0);                       // chunk 2k+2 -> buf0
    STEP(0, 1, sA, sB);             // chunk 2k+1 from buf1
    STEP(1, 1, sB, sA);
    STEP(2, 1, sA, sB);
    STEP(3, 1, sB, sA);
    outP += 1024;
    asm volatile("s_waitcnt vmcnt(16)" ::: "memory");
    __builtin_amdgcn_sched_barrier(0);
    STAGE(1);                       // chunk 2k+3 -> buf1
    STEP(0, 0, sA, sB);             // chunk 2k+2 from buf0
    STEP(1, 0, sB, sA);
    STEP(2, 0, sA, sB);
    STEP(3, 0, sB, sA);
    outP += 1024;
  }

  // ---- tail chunk 255 (buf1): t = 1020..1022 -> rows 1021..1023
  asm volatile("s_waitcnt vmcnt(16)" ::: "memory");
  __builtin_amdgcn_sched_barrier(0);
  STEP(0, 1, sA, sB);
  STEP(1, 1, sB, sA);
  STEP(2, 1, sA, sB);
#undef STEP
#undef STAGE
}

extern "C" void kernel_launch(void* const* d_in, const int* in_sizes, int n_in,
                              void* d_out, int out_size, void* d_ws, size_t ws_size,
                              hipStream_t stream) {
  const float* u     = (const float*)d_in[0];
  const float* noise = (const float*)d_in[1];
  const float* Wrec  = (const float*)d_in[2];
  const float* Win   = (const float*)d_in[3];
  float* out = (float*)d_out;

  const int B = in_sizes[0] / (TT * NIN);  // 512
  hipLaunchKernelGGL(rnn_scan_kernel, dim3(B / NB), dim3(64), 0, stream,
                     u, noise, Wrec, Win, out);
}